// Round 1
// baseline (1999.965 us; speedup 1.0000x reference)
//
#include <hip/hip_runtime.h>
#include <math.h>

#define TT 2048
#define HH 1024
#define NE 40
#define ER 32
#define II 512
#define TOPK 4
#define RSCALE 2.5f

// ---------------- K1: logits = hidden @ router_w^T  (2048x1024 @ 1024x40) ---
// Also zero-inits cnt/cursor (ws is poisoned each call).
__global__ __launch_bounds__(256) void k_logits(const float* __restrict__ hidden,
                                                const float* __restrict__ rw,
                                                float* __restrict__ logits,
                                                int* __restrict__ cnt,
                                                int* __restrict__ cursor) {
  __shared__ float hid[64][129];   // +1 pad: (tok+k)%32 -> 2-way (free)
  __shared__ float rwt[40][129];
  int tid = threadIdx.x;
  int t0 = blockIdx.x * 64;
  if (blockIdx.x == 0 && tid < 32) { cnt[tid] = 0; cursor[tid] = 0; }
  int tsub = tid & 63;
  int g = tid >> 6;                 // expert group: experts g*10 .. g*10+9
  float acc[10];
  #pragma unroll
  for (int j = 0; j < 10; j++) acc[j] = 0.f;
  for (int k0 = 0; k0 < HH; k0 += 128) {
    #pragma unroll
    for (int i = 0; i < 32; i++) {  // 64x128 hidden tile
      int flat = i * 256 + tid;
      int r = flat >> 7, c = flat & 127;
      hid[r][c] = hidden[(size_t)(t0 + r) * HH + k0 + c];
    }
    #pragma unroll
    for (int i = 0; i < 20; i++) {  // 40x128 router tile
      int flat = i * 256 + tid;
      int r = flat >> 7, c = flat & 127;
      rwt[r][c] = rw[(size_t)r * HH + k0 + c];
    }
    __syncthreads();
    #pragma unroll 4
    for (int k = 0; k < 128; k++) {
      float hv = hid[tsub][k];
      #pragma unroll
      for (int j = 0; j < 10; j++) acc[j] += hv * rwt[g * 10 + j][k];  // broadcast
    }
    __syncthreads();
  }
  #pragma unroll
  for (int j = 0; j < 10; j++)
    logits[(size_t)(t0 + tsub) * NE + g * 10 + j] = acc[j];
}

// ---------------- K2: softmax + biased top-4 + out init (one wave/token) ----
__global__ __launch_bounds__(256) void k_route(const float* __restrict__ logits,
                                               const float* __restrict__ bias,
                                               const float* __restrict__ hidden,
                                               float* __restrict__ out,
                                               float* __restrict__ zero_total,
                                               int* __restrict__ cnt,
                                               int* __restrict__ tok4_id,
                                               float* __restrict__ tok4_w) {
  int lane = threadIdx.x & 63;
  int t = blockIdx.x * 4 + (threadIdx.x >> 6);
  float lg = (lane < NE) ? logits[(size_t)t * NE + lane] : -INFINITY;
  float m = lg;
  #pragma unroll
  for (int off = 32; off; off >>= 1) m = fmaxf(m, __shfl_xor(m, off));
  float p = (lane < NE) ? expf(lg - m) : 0.f;
  float s = p;
  #pragma unroll
  for (int off = 32; off; off >>= 1) s += __shfl_xor(s, off);
  float score = p / s;
  float v = (lane < NE) ? score + bias[lane] : -INFINITY;
  int ids[TOPK]; float wv[TOPK];
  #pragma unroll
  for (int k = 0; k < TOPK; k++) {
    float mv = v;
    int mi = (lane < NE) ? lane : 63;
    #pragma unroll
    for (int off = 32; off; off >>= 1) {           // argmax, tie -> lower idx
      float ov = __shfl_xor(mv, off);
      int oi = __shfl_xor(mi, off);
      if (ov > mv || (ov == mv && oi < mi)) { mv = ov; mi = oi; }
    }
    ids[k] = mi;
    wv[k] = RSCALE * __shfl(score, mi);            // weight from UNBIASED score
    if (lane == mi) v = -INFINITY;
  }
  float zt = 0.f;
  #pragma unroll
  for (int k = 0; k < TOPK; k++) if (ids[k] >= ER) zt += wv[k];
  if (lane == 0) {
    zero_total[t] = zt;
    #pragma unroll
    for (int k = 0; k < TOPK; k++) {
      tok4_id[t * TOPK + k] = ids[k];
      tok4_w[t * TOPK + k] = wv[k];
      if (ids[k] < ER) atomicAdd(&cnt[ids[k]], 1);
    }
  }
  // out = hidden * zero_total  (routed part atomically added later)
  for (int j = lane; j < HH; j += 64)
    out[(size_t)t * HH + j] = hidden[(size_t)t * HH + j] * zt;
}

// ---------------- K3: exclusive prefix over 32 counts ----------------------
__global__ void k_scan(const int* __restrict__ cnt, int* __restrict__ offs) {
  if (threadIdx.x == 0) {
    int run = 0;
    for (int e = 0; e < ER; e++) { offs[e] = run; run += cnt[e]; }
  }
}

// ---------------- K4: scatter pairs grouped by expert ----------------------
__global__ __launch_bounds__(256) void k_scatter(const int* __restrict__ tok4_id,
                                                 const float* __restrict__ tok4_w,
                                                 const int* __restrict__ offs,
                                                 int* __restrict__ cursor,
                                                 int* __restrict__ pair_tok,
                                                 float* __restrict__ pair_w) {
  int idx = blockIdx.x * 256 + threadIdx.x;  // TT*4 total
  int id = tok4_id[idx];
  if (id < ER) {
    int slot = atomicAdd(&cursor[id], 1);
    int p = offs[id] + slot;
    pair_tok[p] = idx >> 2;
    pair_w[p] = tok4_w[idx];
  }
}

// ---------------- K5: h = silu(X@Wg^T) * (X@Wu^T), per expert --------------
// grid: 32 experts x 8 col-chunks of 64. Weights read exactly once.
__global__ __launch_bounds__(256) void k_w13(const float* __restrict__ hidden,
                                             const float* __restrict__ w13,
                                             const int* __restrict__ cnt,
                                             const int* __restrict__ offs,
                                             const int* __restrict__ pair_tok,
                                             float* __restrict__ h_buf) {
  int e = blockIdx.x >> 3;
  int n0 = (blockIdx.x & 7) * 64;
  int M = cnt[e];
  if (M == 0) return;
  int base = offs[e];
  __shared__ float X[64][65];
  __shared__ float Wg[64][65];
  __shared__ float Wu[64][65];
  __shared__ int tl[64];
  int tid = threadIdx.x;
  int col = tid & 63;
  int g = tid >> 6;                        // token group: tokens g*16..g*16+15
  const float* wg_base = w13 + (size_t)e * (2 * II) * HH + (size_t)n0 * HH;
  const float* wu_base = wg_base + (size_t)II * HH;
  for (int m0 = 0; m0 < M; m0 += 64) {
    if (tid < 64) tl[tid] = (m0 + tid < M) ? pair_tok[base + m0 + tid] : 0;
    float accg[16], accu[16];
    #pragma unroll
    for (int i = 0; i < 16; i++) { accg[i] = 0.f; accu[i] = 0.f; }
    __syncthreads();
    for (int k0 = 0; k0 < HH; k0 += 64) {
      #pragma unroll
      for (int i = 0; i < 16; i++) {
        int flat = i * 256 + tid;
        int r = flat >> 6, c = flat & 63;
        X[r][c]  = hidden[(size_t)tl[r] * HH + k0 + c];
        Wg[r][c] = wg_base[(size_t)r * HH + k0 + c];
        Wu[r][c] = wu_base[(size_t)r * HH + k0 + c];
      }
      __syncthreads();
      for (int k = 0; k < 64; k++) {
        float wgv = Wg[col][k];              // (col+k)%32 -> 2-way, free
        float wuv = Wu[col][k];
        #pragma unroll
        for (int i = 0; i < 16; i++) {
          float x = X[g * 16 + i][k];        // broadcast within wave
          accg[i] += x * wgv;
          accu[i] += x * wuv;
        }
      }
      __syncthreads();
    }
    #pragma unroll
    for (int i = 0; i < 16; i++) {
      int mm = m0 + g * 16 + i;
      if (mm < M) {
        float gv = accg[i];
        float hv = gv / (1.f + expf(-gv)) * accu[i];   // silu(g)*u
        h_buf[(size_t)(base + mm) * II + n0 + col] = hv;
      }
    }
    __syncthreads();
  }
}

// ---------------- K6: out[t] += w_p * (h_p @ w2[e]^T chunk) ----------------
// grid: 32 experts x 8 row-chunks of 128.
__global__ __launch_bounds__(256) void k_w2(const float* __restrict__ h_buf,
                                            const float* __restrict__ w2,
                                            const int* __restrict__ cnt,
                                            const int* __restrict__ offs,
                                            const int* __restrict__ pair_tok,
                                            const float* __restrict__ pair_w,
                                            float* __restrict__ out) {
  int e = blockIdx.x >> 3;
  int h0 = (blockIdx.x & 7) * 128;
  int M = cnt[e];
  if (M == 0) return;
  int base = offs[e];
  __shared__ float Hs[64][65];
  __shared__ float Wt[128][65];
  __shared__ int tl[64];
  __shared__ float wl[64];
  int tid = threadIdx.x;
  int col = tid & 63;
  int g = tid >> 6;
  const float* w_base = w2 + (size_t)e * HH * II + (size_t)h0 * II;
  for (int m0 = 0; m0 < M; m0 += 64) {
    if (tid < 64) {
      int ok = (m0 + tid) < M;
      tl[tid] = ok ? pair_tok[base + m0 + tid] : 0;
      wl[tid] = ok ? pair_w[base + m0 + tid] : 0.f;
    }
    float acc0[16], acc1[16];
    #pragma unroll
    for (int i = 0; i < 16; i++) { acc0[i] = 0.f; acc1[i] = 0.f; }
    __syncthreads();
    for (int k0 = 0; k0 < II; k0 += 64) {
      #pragma unroll
      for (int i = 0; i < 16; i++) {         // 64x64 h tile (padded rows: junk, masked at store)
        int flat = i * 256 + tid;
        int r = flat >> 6, c = flat & 63;
        Hs[r][c] = h_buf[(size_t)(base + m0 + r) * II + k0 + c];
      }
      #pragma unroll
      for (int i = 0; i < 32; i++) {         // 128x64 w2 tile
        int flat = i * 256 + tid;
        int r = flat >> 6, c = flat & 63;
        Wt[r][c] = w_base[(size_t)r * II + k0 + c];
      }
      __syncthreads();
      for (int k = 0; k < 64; k++) {
        float w0 = Wt[col][k];
        float w1 = Wt[col + 64][k];
        #pragma unroll
        for (int i = 0; i < 16; i++) {
          float x = Hs[g * 16 + i][k];
          acc0[i] += x * w0;
          acc1[i] += x * w1;
        }
      }
      __syncthreads();
    }
    #pragma unroll
    for (int i = 0; i < 16; i++) {
      int mm = m0 + g * 16 + i;
      if (mm < M) {
        int t = tl[g * 16 + i];
        float wp = wl[g * 16 + i];
        atomicAdd(&out[(size_t)t * HH + h0 + col], acc0[i] * wp);
        atomicAdd(&out[(size_t)t * HH + h0 + 64 + col], acc1[i] * wp);
      }
    }
    __syncthreads();   // epilogue reads tl/wl; protect against next m0's rewrite
  }
}

extern "C" void kernel_launch(void* const* d_in, const int* in_sizes, int n_in,
                              void* d_out, int out_size, void* d_ws, size_t ws_size,
                              hipStream_t stream) {
  const float* hidden = (const float*)d_in[0];
  const float* rw     = (const float*)d_in[1];
  const float* bias   = (const float*)d_in[2];
  const float* w13    = (const float*)d_in[3];
  const float* w2     = (const float*)d_in[4];
  float* out = (float*)d_out;

  // ws layout (floats): logits[TT*40] | zero_total[TT] | cnt[32] offs[32] cursor[32]
  //                     | tok4_id[TT*4] tok4_w[TT*4] | pair_tok[TT*4] pair_w[TT*4]
  //                     | h_buf[(TT*4+64)*II]   (~17.4 MB total)
  float* ws_f = (float*)d_ws;
  float* logits = ws_f;
  float* zero_total = logits + (size_t)TT * NE;
  int* cnt = (int*)(zero_total + TT);
  int* offs = cnt + 32;
  int* cursor = offs + 32;
  int* tok4_id = cursor + 32;
  float* tok4_w = (float*)(tok4_id + TT * TOPK);
  int* pair_tok = (int*)(tok4_w + TT * TOPK);
  float* pair_w = (float*)(pair_tok + TT * TOPK);
  float* h_buf = pair_w + TT * TOPK;      // (TT*4 + 64) rows of II

  k_logits<<<dim3(TT / 64), dim3(256), 0, stream>>>(hidden, rw, logits, cnt, cursor);
  k_route<<<dim3(TT / 4), dim3(256), 0, stream>>>(logits, bias, hidden, out,
                                                  zero_total, cnt, tok4_id, tok4_w);
  k_scan<<<dim3(1), dim3(64), 0, stream>>>(cnt, offs);
  k_scatter<<<dim3(TT * TOPK / 256), dim3(256), 0, stream>>>(tok4_id, tok4_w, offs,
                                                             cursor, pair_tok, pair_w);
  k_w13<<<dim3(256), dim3(256), 0, stream>>>(hidden, w13, cnt, offs, pair_tok, h_buf);
  k_w2<<<dim3(256), dim3(256), 0, stream>>>(h_buf, w2, cnt, offs, pair_tok, pair_w, out);
}

// Round 2
// 427.949 us; speedup vs baseline: 4.6734x; 4.6734x over previous
//
#include <hip/hip_runtime.h>
#include <math.h>

#define TT 2048
#define HH 1024
#define NE 40
#define ER 32
#define II 512
#define TOPK 4
#define RSCALE 2.5f
#define MAXW 160   // max work items: 8192/64 + 32

typedef __bf16 bf16x8 __attribute__((ext_vector_type(8)));
typedef float f32x4 __attribute__((ext_vector_type(4)));

// ---------------- K1: logits = hidden @ router_w^T  (2048x1024 @ 1024x40) ---
__global__ __launch_bounds__(256) void k_logits(const float* __restrict__ hidden,
                                                const float* __restrict__ rw,
                                                float* __restrict__ logits,
                                                int* __restrict__ cnt,
                                                int* __restrict__ cursor) {
  __shared__ float hid[64][129];
  __shared__ float rwt[40][129];
  int tid = threadIdx.x;
  int t0 = blockIdx.x * 64;
  if (blockIdx.x == 0 && tid < 32) { cnt[tid] = 0; cursor[tid] = 0; }
  int tsub = tid & 63;
  int g = tid >> 6;                 // expert group: experts g*10 .. g*10+9
  float acc[10];
  #pragma unroll
  for (int j = 0; j < 10; j++) acc[j] = 0.f;
  for (int k0 = 0; k0 < HH; k0 += 128) {
    #pragma unroll
    for (int i = 0; i < 32; i++) {
      int flat = i * 256 + tid;
      int r = flat >> 7, c = flat & 127;
      hid[r][c] = hidden[(size_t)(t0 + r) * HH + k0 + c];
    }
    #pragma unroll
    for (int i = 0; i < 20; i++) {
      int flat = i * 256 + tid;
      int r = flat >> 7, c = flat & 127;
      rwt[r][c] = rw[(size_t)r * HH + k0 + c];
    }
    __syncthreads();
    #pragma unroll 4
    for (int k = 0; k < 128; k++) {
      float hv = hid[tsub][k];
      #pragma unroll
      for (int j = 0; j < 10; j++) acc[j] += hv * rwt[g * 10 + j][k];
    }
    __syncthreads();
  }
  #pragma unroll
  for (int j = 0; j < 10; j++)
    logits[(size_t)(t0 + tsub) * NE + g * 10 + j] = acc[j];
}

// ---------------- K2: softmax + top-4 + out init + hidden->bf16 ------------
__global__ __launch_bounds__(256) void k_route(const float* __restrict__ logits,
                                               const float* __restrict__ bias,
                                               const float* __restrict__ hidden,
                                               float* __restrict__ out,
                                               int* __restrict__ cnt,
                                               int* __restrict__ tok4_id,
                                               float* __restrict__ tok4_w,
                                               __bf16* __restrict__ hid_bf) {
  int lane = threadIdx.x & 63;
  int t = blockIdx.x * 4 + (threadIdx.x >> 6);
  float lg = (lane < NE) ? logits[(size_t)t * NE + lane] : -INFINITY;
  float m = lg;
  #pragma unroll
  for (int off = 32; off; off >>= 1) m = fmaxf(m, __shfl_xor(m, off));
  float p = (lane < NE) ? expf(lg - m) : 0.f;
  float s = p;
  #pragma unroll
  for (int off = 32; off; off >>= 1) s += __shfl_xor(s, off);
  float score = p / s;
  float v = (lane < NE) ? score + bias[lane] : -INFINITY;
  int ids[TOPK]; float wv[TOPK];
  #pragma unroll
  for (int k = 0; k < TOPK; k++) {
    float mv = v;
    int mi = (lane < NE) ? lane : 63;
    #pragma unroll
    for (int off = 32; off; off >>= 1) {
      float ov = __shfl_xor(mv, off);
      int oi = __shfl_xor(mi, off);
      if (ov > mv || (ov == mv && oi < mi)) { mv = ov; mi = oi; }
    }
    ids[k] = mi;
    wv[k] = RSCALE * __shfl(score, mi);
    if (lane == mi) v = -INFINITY;
  }
  float zt = 0.f;
  #pragma unroll
  for (int k = 0; k < TOPK; k++) if (ids[k] >= ER) zt += wv[k];
  if (lane == 0) {
    #pragma unroll
    for (int k = 0; k < TOPK; k++) {
      tok4_id[t * TOPK + k] = ids[k];
      tok4_w[t * TOPK + k] = wv[k];
      if (ids[k] < ER) atomicAdd(&cnt[ids[k]], 1);
    }
  }
  for (int j = lane; j < HH; j += 64) {
    float hv = hidden[(size_t)t * HH + j];
    out[(size_t)t * HH + j] = hv * zt;
    hid_bf[(size_t)t * HH + j] = (__bf16)hv;
  }
}

// ---------------- K3: prefix scan + work-list build ------------------------
__global__ void k_scan(const int* __restrict__ cnt, int* __restrict__ offs,
                       int* __restrict__ wl_e, int* __restrict__ wl_m0,
                       int* __restrict__ nwork) {
  if (threadIdx.x == 0) {
    int run = 0, nw = 0;
    for (int e = 0; e < ER; e++) {
      offs[e] = run;
      for (int m0 = 0; m0 < cnt[e]; m0 += 64) { wl_e[nw] = e; wl_m0[nw] = m0; nw++; }
      run += cnt[e];
    }
    *nwork = nw;
  }
}

// ---------------- K4: scatter pairs grouped by expert ----------------------
__global__ __launch_bounds__(256) void k_scatter(const int* __restrict__ tok4_id,
                                                 const float* __restrict__ tok4_w,
                                                 const int* __restrict__ offs,
                                                 int* __restrict__ cursor,
                                                 int* __restrict__ pair_tok,
                                                 float* __restrict__ pair_w) {
  int idx = blockIdx.x * 256 + threadIdx.x;
  int id = tok4_id[idx];
  if (id < ER) {
    int slot = atomicAdd(&cursor[id], 1);
    int p = offs[id] + slot;
    pair_tok[p] = idx >> 2;
    pair_w[p] = tok4_w[idx];
  }
}

// ---------------- K5: h = silu(X@Wg^T)*(X@Wu^T), bf16 MFMA -----------------
// grid: (MAXW work items) x (8 gate-chunks of 64). Block: 64 pairs x (64 gate
// + 64 up cols). Waves 2x2: rows wr*32..+32, gate cols wc*32..+32.
__global__ __launch_bounds__(256) void k_w13(const __bf16* __restrict__ hid_bf,
                                             const float* __restrict__ w13,
                                             const int* __restrict__ cnt,
                                             const int* __restrict__ offs,
                                             const int* __restrict__ pair_tok,
                                             const int* __restrict__ wl_e,
                                             const int* __restrict__ wl_m0,
                                             const int* __restrict__ nwork,
                                             __bf16* __restrict__ h_buf) {
  int bx = blockIdx.x;
  if (bx >= *nwork) return;
  int e = wl_e[bx], m0w = wl_m0[bx];
  int M = cnt[e] - m0w; if (M > 64) M = 64;
  int base = offs[e] + m0w;
  int n0 = blockIdx.y * 64;

  __shared__ __bf16 As[64][72];      // pairs x k   (+8 pad: 2-way banks, free)
  __shared__ __bf16 Bs[128][72];     // [0:64)=gate rows, [64:128)=up rows
  __shared__ int tl[64];

  int tid = threadIdx.x;
  int lane = tid & 63, wid = tid >> 6;
  int wr = wid & 1, wc = wid >> 1;
  int quad = lane >> 4, rr = lane & 15;

  if (tid < 64) tl[tid] = pair_tok[base + ((tid < M) ? tid : 0)];

  const float* wg_base = w13 + (size_t)e * (2 * II) * HH + (size_t)n0 * HH;
  const float* wu_base = w13 + (size_t)e * (2 * II) * HH + (size_t)(II + n0) * HH;

  f32x4 accg[2][2] = {};
  f32x4 accu[2][2] = {};
  __syncthreads();

  for (int k0 = 0; k0 < HH; k0 += 64) {
    #pragma unroll
    for (int p = 0; p < 2; p++) {            // A: 64 rows x 64 bf16 (16B/thr)
      int s = p * 256 + tid;
      int r = s >> 3, c = (s & 7) * 8;
      *(uint4*)&As[r][c] = *(const uint4*)(hid_bf + (size_t)tl[r] * HH + k0 + c);
    }
    #pragma unroll
    for (int p = 0; p < 8; p++) {            // B: 128 rows x 64 fp32 -> bf16
      int s = p * 256 + tid;
      int r = s >> 4, c = (s & 15) * 4;
      const float* src = ((r < 64) ? (wg_base + (size_t)r * HH)
                                   : (wu_base + (size_t)(r - 64) * HH)) + k0 + c;
      float4 v = *(const float4*)src;
      union { __bf16 h[4]; uint2 u; } pk;
      pk.h[0] = (__bf16)v.x; pk.h[1] = (__bf16)v.y;
      pk.h[2] = (__bf16)v.z; pk.h[3] = (__bf16)v.w;
      *(uint2*)&Bs[r][c] = pk.u;
    }
    __syncthreads();
    #pragma unroll
    for (int ks = 0; ks < 2; ks++) {
      int kb = ks * 32 + quad * 8;
      bf16x8 a0  = *(const bf16x8*)&As[wr * 32 + rr][kb];
      bf16x8 a1  = *(const bf16x8*)&As[wr * 32 + 16 + rr][kb];
      bf16x8 bg0 = *(const bf16x8*)&Bs[wc * 32 + rr][kb];
      bf16x8 bg1 = *(const bf16x8*)&Bs[wc * 32 + 16 + rr][kb];
      bf16x8 bu0 = *(const bf16x8*)&Bs[64 + wc * 32 + rr][kb];
      bf16x8 bu1 = *(const bf16x8*)&Bs[64 + wc * 32 + 16 + rr][kb];
      accg[0][0] = __builtin_amdgcn_mfma_f32_16x16x32_bf16(a0, bg0, accg[0][0], 0, 0, 0);
      accg[0][1] = __builtin_amdgcn_mfma_f32_16x16x32_bf16(a0, bg1, accg[0][1], 0, 0, 0);
      accg[1][0] = __builtin_amdgcn_mfma_f32_16x16x32_bf16(a1, bg0, accg[1][0], 0, 0, 0);
      accg[1][1] = __builtin_amdgcn_mfma_f32_16x16x32_bf16(a1, bg1, accg[1][1], 0, 0, 0);
      accu[0][0] = __builtin_amdgcn_mfma_f32_16x16x32_bf16(a0, bu0, accu[0][0], 0, 0, 0);
      accu[0][1] = __builtin_amdgcn_mfma_f32_16x16x32_bf16(a0, bu1, accu[0][1], 0, 0, 0);
      accu[1][0] = __builtin_amdgcn_mfma_f32_16x16x32_bf16(a1, bu0, accu[1][0], 0, 0, 0);
      accu[1][1] = __builtin_amdgcn_mfma_f32_16x16x32_bf16(a1, bu1, accu[1][1], 0, 0, 0);
    }
    __syncthreads();
  }
  // epilogue: C/D layout col=lane&15, row=quad*4+reg (m89/m91 verified)
  #pragma unroll
  for (int i = 0; i < 2; i++)
    #pragma unroll
    for (int j = 0; j < 2; j++)
      #pragma unroll
      for (int l = 0; l < 4; l++) {
        int m = wr * 32 + i * 16 + quad * 4 + l;
        if (m < M) {
          float g = accg[i][j][l], u = accu[i][j][l];
          float hv = g / (1.f + expf(-g)) * u;
          h_buf[(size_t)(base + m) * II + n0 + wc * 32 + j * 16 + rr] = (__bf16)hv;
        }
      }
}

// ---------------- K6: out[t] += w_p * (h @ w2[e]^T), bf16 MFMA -------------
// grid: MAXW x (8 chunks of 128 H-cols). Waves 2x2: rows wr*32, cols wc*64.
__global__ __launch_bounds__(256) void k_w2(const __bf16* __restrict__ h_buf,
                                            const float* __restrict__ w2,
                                            const int* __restrict__ cnt,
                                            const int* __restrict__ offs,
                                            const int* __restrict__ pair_tok,
                                            const float* __restrict__ pair_w,
                                            const int* __restrict__ wl_e,
                                            const int* __restrict__ wl_m0,
                                            const int* __restrict__ nwork,
                                            float* __restrict__ out) {
  int bx = blockIdx.x;
  if (bx >= *nwork) return;
  int e = wl_e[bx], m0w = wl_m0[bx];
  int M = cnt[e] - m0w; if (M > 64) M = 64;
  int base = offs[e] + m0w;
  int h0 = blockIdx.y * 128;

  __shared__ __bf16 As[64][72];
  __shared__ __bf16 Bs[128][72];
  __shared__ int tl[64];
  __shared__ float wl[64];

  int tid = threadIdx.x;
  int lane = tid & 63, wid = tid >> 6;
  int wr = wid & 1, wc = wid >> 1;
  int quad = lane >> 4, rr = lane & 15;

  if (tid < 64) {
    int ok = tid < M;
    tl[tid] = ok ? pair_tok[base + tid] : 0;
    wl[tid] = ok ? pair_w[base + tid] : 0.f;
  }
  const __bf16* h_base = h_buf + (size_t)base * II;
  const float* w_base = w2 + (size_t)e * HH * II + (size_t)h0 * II;

  f32x4 acc[2][4] = {};
  __syncthreads();

  for (int k0 = 0; k0 < II; k0 += 64) {
    #pragma unroll
    for (int p = 0; p < 2; p++) {            // A: 64 contiguous h rows
      int s = p * 256 + tid;
      int r = s >> 3, c = (s & 7) * 8;
      *(uint4*)&As[r][c] = *(const uint4*)(h_base + (size_t)r * II + k0 + c);
    }
    #pragma unroll
    for (int p = 0; p < 8; p++) {            // B: 128 rows x 64 fp32 -> bf16
      int s = p * 256 + tid;
      int r = s >> 4, c = (s & 15) * 4;
      float4 v = *(const float4*)(w_base + (size_t)r * II + k0 + c);
      union { __bf16 h[4]; uint2 u; } pk;
      pk.h[0] = (__bf16)v.x; pk.h[1] = (__bf16)v.y;
      pk.h[2] = (__bf16)v.z; pk.h[3] = (__bf16)v.w;
      *(uint2*)&Bs[r][c] = pk.u;
    }
    __syncthreads();
    #pragma unroll
    for (int ks = 0; ks < 2; ks++) {
      int kb = ks * 32 + quad * 8;
      bf16x8 a0 = *(const bf16x8*)&As[wr * 32 + rr][kb];
      bf16x8 a1 = *(const bf16x8*)&As[wr * 32 + 16 + rr][kb];
      bf16x8 b0 = *(const bf16x8*)&Bs[wc * 64 + rr][kb];
      bf16x8 b1 = *(const bf16x8*)&Bs[wc * 64 + 16 + rr][kb];
      bf16x8 b2 = *(const bf16x8*)&Bs[wc * 64 + 32 + rr][kb];
      bf16x8 b3 = *(const bf16x8*)&Bs[wc * 64 + 48 + rr][kb];
      acc[0][0] = __builtin_amdgcn_mfma_f32_16x16x32_bf16(a0, b0, acc[0][0], 0, 0, 0);
      acc[0][1] = __builtin_amdgcn_mfma_f32_16x16x32_bf16(a0, b1, acc[0][1], 0, 0, 0);
      acc[0][2] = __builtin_amdgcn_mfma_f32_16x16x32_bf16(a0, b2, acc[0][2], 0, 0, 0);
      acc[0][3] = __builtin_amdgcn_mfma_f32_16x16x32_bf16(a0, b3, acc[0][3], 0, 0, 0);
      acc[1][0] = __builtin_amdgcn_mfma_f32_16x16x32_bf16(a1, b0, acc[1][0], 0, 0, 0);
      acc[1][1] = __builtin_amdgcn_mfma_f32_16x16x32_bf16(a1, b1, acc[1][1], 0, 0, 0);
      acc[1][2] = __builtin_amdgcn_mfma_f32_16x16x32_bf16(a1, b2, acc[1][2], 0, 0, 0);
      acc[1][3] = __builtin_amdgcn_mfma_f32_16x16x32_bf16(a1, b3, acc[1][3], 0, 0, 0);
    }
    __syncthreads();
  }
  #pragma unroll
  for (int i = 0; i < 2; i++)
    #pragma unroll
    for (int l = 0; l < 4; l++) {
      int m = wr * 32 + i * 16 + quad * 4 + l;
      if (m < M) {
        int t = tl[m];
        float wp = wl[m];
        #pragma unroll
        for (int j = 0; j < 4; j++)
          atomicAdd(&out[(size_t)t * HH + h0 + wc * 64 + j * 16 + rr], acc[i][j][l] * wp);
      }
    }
}

extern "C" void kernel_launch(void* const* d_in, const int* in_sizes, int n_in,
                              void* d_out, int out_size, void* d_ws, size_t ws_size,
                              hipStream_t stream) {
  const float* hidden = (const float*)d_in[0];
  const float* rw     = (const float*)d_in[1];
  const float* bias   = (const float*)d_in[2];
  const float* w13    = (const float*)d_in[3];
  const float* w2     = (const float*)d_in[4];
  float* out = (float*)d_out;

  float* ws_f = (float*)d_ws;
  float* logits = ws_f;                                   // TT*40
  int* cnt = (int*)(logits + (size_t)TT * NE + TT);       // (+TT unused slack)
  int* offs = cnt + 32;
  int* cursor = offs + 32;
  int* tok4_id = cursor + 32;                             // TT*4
  float* tok4_w = (float*)(tok4_id + TT * TOPK);          // TT*4
  int* pair_tok = (int*)(tok4_w + TT * TOPK);             // TT*4
  float* pair_w = (float*)(pair_tok + TT * TOPK);         // TT*4
  int* wl_e = (int*)(pair_w + TT * TOPK);                 // 192
  int* wl_m0 = wl_e + 192;                                // 192
  int* nwork = wl_m0 + 192;                               // 64 (pad for align)
  __bf16* hid_bf = (__bf16*)(nwork + 64);                 // TT*HH bf16 (16B-aligned)
  __bf16* h_buf = hid_bf + (size_t)TT * HH;               // (TT*4+64)*II bf16

  k_logits<<<dim3(TT / 64), dim3(256), 0, stream>>>(hidden, rw, logits, cnt, cursor);
  k_route<<<dim3(TT / 4), dim3(256), 0, stream>>>(logits, bias, hidden, out,
                                                  cnt, tok4_id, tok4_w, hid_bf);
  k_scan<<<dim3(1), dim3(64), 0, stream>>>(cnt, offs, wl_e, wl_m0, nwork);
  k_scatter<<<dim3(TT * TOPK / 256), dim3(256), 0, stream>>>(tok4_id, tok4_w, offs,
                                                             cursor, pair_tok, pair_w);
  k_w13<<<dim3(MAXW, 8), dim3(256), 0, stream>>>(hid_bf, w13, cnt, offs, pair_tok,
                                                 wl_e, wl_m0, nwork, h_buf);
  k_w2<<<dim3(MAXW, 8), dim3(256), 0, stream>>>(h_buf, w2, cnt, offs, pair_tok, pair_w,
                                                wl_e, wl_m0, nwork, out);
}

// Round 4
// 363.108 us; speedup vs baseline: 5.5079x; 1.1786x over previous
//
#include <hip/hip_runtime.h>
#include <math.h>

#define TT 2048
#define HH 1024
#define NE 40
#define ER 32
#define II 512
#define TOPK 4
#define RSCALE 2.5f
#define MAXW 96    // max m-tiles of 128: 8192/128 + 32

typedef __bf16 bf16x8 __attribute__((ext_vector_type(8)));
typedef float f32x4 __attribute__((ext_vector_type(4)));

// ---------------- K1: logits = hidden @ router_w^T, fp32 vector ------------
// One wave per token; lanes split K (16 elems each); butterfly reduce.
// fp32 is REQUIRED here: bf16 logit error (~2.6e-3) flips top-4 selection.
__global__ __launch_bounds__(256) void k_logits(const float* __restrict__ hidden,
                                                const float* __restrict__ rw,
                                                float* __restrict__ logits,
                                                int* __restrict__ cnt,
                                                int* __restrict__ cursor) {
  int tid = threadIdx.x;
  if (blockIdx.x == 0 && tid < 32) { cnt[tid] = 0; cursor[tid] = 0; }
  int lane = tid & 63;
  int t = blockIdx.x * 4 + (tid >> 6);
  const float* hrow = hidden + (size_t)t * HH;
  float4 hv[4];
  #pragma unroll
  for (int c = 0; c < 4; c++)
    hv[c] = *(const float4*)(hrow + c * 256 + lane * 4);
  float mylg = 0.f;
  for (int e = 0; e < NE; e++) {
    const float* wrow = rw + (size_t)e * HH;
    float p = 0.f;
    #pragma unroll
    for (int c = 0; c < 4; c++) {
      float4 wv = *(const float4*)(wrow + c * 256 + lane * 4);
      p += hv[c].x * wv.x + hv[c].y * wv.y + hv[c].z * wv.z + hv[c].w * wv.w;
    }
    #pragma unroll
    for (int off = 32; off; off >>= 1) p += __shfl_xor(p, off);
    if (lane == e) mylg = p;
  }
  if (lane < NE) logits[(size_t)t * NE + lane] = mylg;
}

// ---------------- K2: softmax + top-4 + out init + hidden->bf16 ------------
__global__ __launch_bounds__(256) void k_route(const float* __restrict__ logits,
                                               const float* __restrict__ bias,
                                               const float* __restrict__ hidden,
                                               float* __restrict__ out,
                                               int* __restrict__ cnt,
                                               int* __restrict__ tok4_id,
                                               float* __restrict__ tok4_w,
                                               __bf16* __restrict__ hid_bf) {
  int lane = threadIdx.x & 63;
  int t = blockIdx.x * 4 + (threadIdx.x >> 6);
  float lg = (lane < NE) ? logits[(size_t)t * NE + lane] : -INFINITY;
  float m = lg;
  #pragma unroll
  for (int off = 32; off; off >>= 1) m = fmaxf(m, __shfl_xor(m, off));
  float p = (lane < NE) ? expf(lg - m) : 0.f;
  float s = p;
  #pragma unroll
  for (int off = 32; off; off >>= 1) s += __shfl_xor(s, off);
  float score = p / s;
  float v = (lane < NE) ? score + bias[lane] : -INFINITY;
  int ids[TOPK]; float wv[TOPK];
  #pragma unroll
  for (int k = 0; k < TOPK; k++) {
    float mv = v;
    int mi = (lane < NE) ? lane : 63;
    #pragma unroll
    for (int off = 32; off; off >>= 1) {
      float ov = __shfl_xor(mv, off);
      int oi = __shfl_xor(mi, off);
      if (ov > mv || (ov == mv && oi < mi)) { mv = ov; mi = oi; }
    }
    ids[k] = mi;
    wv[k] = RSCALE * __shfl(score, mi);
    if (lane == mi) v = -INFINITY;
  }
  float zt = 0.f;
  #pragma unroll
  for (int k = 0; k < TOPK; k++) if (ids[k] >= ER) zt += wv[k];
  if (lane == 0) {
    #pragma unroll
    for (int k = 0; k < TOPK; k++) {
      tok4_id[t * TOPK + k] = ids[k];
      tok4_w[t * TOPK + k] = wv[k];
      if (ids[k] < ER) atomicAdd(&cnt[ids[k]], 1);
    }
  }
  #pragma unroll
  for (int c = 0; c < 4; c++) {
    int j = c * 256 + lane * 4;
    float4 h4 = *(const float4*)(hidden + (size_t)t * HH + j);
    float4 o4 = make_float4(h4.x * zt, h4.y * zt, h4.z * zt, h4.w * zt);
    *(float4*)(out + (size_t)t * HH + j) = o4;
    union { __bf16 h[4]; uint2 u; } pk;
    pk.h[0] = (__bf16)h4.x; pk.h[1] = (__bf16)h4.y;
    pk.h[2] = (__bf16)h4.z; pk.h[3] = (__bf16)h4.w;
    *(uint2*)(hid_bf + (size_t)t * HH + j) = pk.u;
  }
}

// ---------------- K3: one-wave prefix scan + work-list build ---------------
__global__ void k_scan(const int* __restrict__ cnt, int* __restrict__ offs,
                       int* __restrict__ wl_e, int* __restrict__ wl_m0,
                       int* __restrict__ nwork) {
  int lane = threadIdx.x;
  int c = (lane < ER) ? cnt[lane] : 0;
  int ts = (c + 127) >> 7;
  int ps = c, pt = ts;
  #pragma unroll
  for (int off = 1; off < 32; off <<= 1) {
    int v1 = __shfl_up(ps, off);
    int v2 = __shfl_up(pt, off);
    if (lane >= off) { ps += v1; pt += v2; }
  }
  if (lane < ER) {
    offs[lane] = ps - c;
    int tb = pt - ts;
    for (int i = 0; i < ts; i++) { wl_e[tb + i] = lane; wl_m0[tb + i] = i * 128; }
  }
  if (lane == 31) *nwork = pt;
}

// ---------------- K4: scatter pairs grouped by expert ----------------------
__global__ __launch_bounds__(256) void k_scatter(const int* __restrict__ tok4_id,
                                                 const float* __restrict__ tok4_w,
                                                 const int* __restrict__ offs,
                                                 int* __restrict__ cursor,
                                                 int* __restrict__ pair_tok,
                                                 float* __restrict__ pair_w) {
  int idx = blockIdx.x * 256 + threadIdx.x;
  int id = tok4_id[idx];
  if (id < ER) {
    int slot = atomicAdd(&cursor[id], 1);
    int p = offs[id] + slot;
    pair_tok[p] = idx >> 2;
    pair_w[p] = tok4_w[idx];
  }
}

// ---------------- K5: h = silu(X@Wg^T)*(X@Wu^T), M=128 tile ----------------
__global__ __launch_bounds__(256) void k_w13(const __bf16* __restrict__ hid_bf,
                                             const float* __restrict__ w13,
                                             const int* __restrict__ cnt,
                                             const int* __restrict__ offs,
                                             const int* __restrict__ pair_tok,
                                             const int* __restrict__ wl_e,
                                             const int* __restrict__ wl_m0,
                                             const int* __restrict__ nwork,
                                             __bf16* __restrict__ h_buf) {
  int bx = blockIdx.x;
  if (bx >= *nwork) return;
  int e = wl_e[bx], m0w = wl_m0[bx];
  int M = cnt[e] - m0w; if (M > 128) M = 128;
  int base = offs[e] + m0w;
  int n0 = blockIdx.y * 64;

  __shared__ __bf16 As[128][72];   // pairs x k
  __shared__ __bf16 Bs[128][72];   // [0:64)=gate rows, [64:128)=up rows
  __shared__ int tl[128];

  int tid = threadIdx.x;
  int lane = tid & 63, wid = tid >> 6;
  int wr = wid & 1, wc = wid >> 1;
  int quad = lane >> 4, rr = lane & 15;

  if (tid < 128) tl[tid] = pair_tok[base + ((tid < M) ? tid : 0)];

  const float* wg_base = w13 + (size_t)e * (2 * II) * HH + (size_t)n0 * HH;
  const float* wu_base = w13 + (size_t)e * (2 * II) * HH + (size_t)(II + n0) * HH;

  f32x4 accg[4][2] = {};
  f32x4 accu[4][2] = {};
  __syncthreads();

  for (int k0 = 0; k0 < HH; k0 += 64) {
    #pragma unroll
    for (int p = 0; p < 4; p++) {            // A: 128 x 64 bf16 (16B/thr)
      int s = p * 256 + tid;
      int r = s >> 3, c = (s & 7) * 8;
      *(uint4*)&As[r][c] = *(const uint4*)(hid_bf + (size_t)tl[r] * HH + k0 + c);
    }
    #pragma unroll
    for (int p = 0; p < 8; p++) {            // B: 128 x 64 fp32 -> bf16
      int s = p * 256 + tid;
      int r = s >> 4, c = (s & 15) * 4;
      const float* src = ((r < 64) ? (wg_base + (size_t)r * HH)
                                   : (wu_base + (size_t)(r - 64) * HH)) + k0 + c;
      float4 v = *(const float4*)src;
      union { __bf16 h[4]; uint2 u; } pk;
      pk.h[0] = (__bf16)v.x; pk.h[1] = (__bf16)v.y;
      pk.h[2] = (__bf16)v.z; pk.h[3] = (__bf16)v.w;
      *(uint2*)&Bs[r][c] = pk.u;
    }
    __syncthreads();
    #pragma unroll
    for (int ks = 0; ks < 2; ks++) {
      int kb = ks * 32 + quad * 8;
      bf16x8 a[4], bg[2], bu[2];
      #pragma unroll
      for (int i = 0; i < 4; i++) a[i] = *(const bf16x8*)&As[wr * 64 + i * 16 + rr][kb];
      #pragma unroll
      for (int j = 0; j < 2; j++) {
        bg[j] = *(const bf16x8*)&Bs[wc * 32 + j * 16 + rr][kb];
        bu[j] = *(const bf16x8*)&Bs[64 + wc * 32 + j * 16 + rr][kb];
      }
      #pragma unroll
      for (int i = 0; i < 4; i++)
        #pragma unroll
        for (int j = 0; j < 2; j++) {
          accg[i][j] = __builtin_amdgcn_mfma_f32_16x16x32_bf16(a[i], bg[j], accg[i][j], 0, 0, 0);
          accu[i][j] = __builtin_amdgcn_mfma_f32_16x16x32_bf16(a[i], bu[j], accu[i][j], 0, 0, 0);
        }
    }
    __syncthreads();
  }
  #pragma unroll
  for (int i = 0; i < 4; i++)
    #pragma unroll
    for (int j = 0; j < 2; j++)
      #pragma unroll
      for (int l = 0; l < 4; l++) {
        int m = wr * 64 + i * 16 + quad * 4 + l;
        if (m < M) {
          float g = accg[i][j][l], u = accu[i][j][l];
          float hv = g / (1.f + expf(-g)) * u;
          h_buf[(size_t)(base + m) * II + n0 + wc * 32 + j * 16 + rr] = (__bf16)hv;
        }
      }
}

// ---------------- K6: out[t] += w_p * (h @ w2[e]^T), M=128 tile ------------
__global__ __launch_bounds__(256) void k_w2(const __bf16* __restrict__ h_buf,
                                            const float* __restrict__ w2,
                                            const int* __restrict__ cnt,
                                            const int* __restrict__ offs,
                                            const int* __restrict__ pair_tok,
                                            const float* __restrict__ pair_w,
                                            const int* __restrict__ wl_e,
                                            const int* __restrict__ wl_m0,
                                            const int* __restrict__ nwork,
                                            float* __restrict__ out) {
  int bx = blockIdx.x;
  if (bx >= *nwork) return;
  int e = wl_e[bx], m0w = wl_m0[bx];
  int M = cnt[e] - m0w; if (M > 128) M = 128;
  int base = offs[e] + m0w;
  int h0 = blockIdx.y * 128;

  __shared__ __bf16 As[128][72];
  __shared__ __bf16 Bs[128][72];
  __shared__ int tl[128];
  __shared__ float wl[128];

  int tid = threadIdx.x;
  int lane = tid & 63, wid = tid >> 6;
  int wr = wid & 1, wc = wid >> 1;
  int quad = lane >> 4, rr = lane & 15;

  if (tid < 128) {
    int ok = tid < M;
    tl[tid] = ok ? pair_tok[base + tid] : 0;
    wl[tid] = ok ? pair_w[base + tid] : 0.f;
  }
  const __bf16* h_base = h_buf + (size_t)base * II;
  const float* w_base = w2 + (size_t)e * HH * II + (size_t)h0 * II;

  f32x4 acc[4][4] = {};
  __syncthreads();

  for (int k0 = 0; k0 < II; k0 += 64) {
    #pragma unroll
    for (int p = 0; p < 4; p++) {            // A: 128 contiguous h rows
      int s = p * 256 + tid;
      int r = s >> 3, c = (s & 7) * 8;
      *(uint4*)&As[r][c] = *(const uint4*)(h_base + (size_t)r * II + k0 + c);
    }
    #pragma unroll
    for (int p = 0; p < 8; p++) {            // B: 128 x 64 fp32 -> bf16
      int s = p * 256 + tid;
      int r = s >> 4, c = (s & 15) * 4;
      float4 v = *(const float4*)(w_base + (size_t)r * II + k0 + c);
      union { __bf16 h[4]; uint2 u; } pk;
      pk.h[0] = (__bf16)v.x; pk.h[1] = (__bf16)v.y;
      pk.h[2] = (__bf16)v.z; pk.h[3] = (__bf16)v.w;
      *(uint2*)&Bs[r][c] = pk.u;
    }
    __syncthreads();
    #pragma unroll
    for (int ks = 0; ks < 2; ks++) {
      int kb = ks * 32 + quad * 8;
      bf16x8 a[4], b[4];
      #pragma unroll
      for (int i = 0; i < 4; i++) a[i] = *(const bf16x8*)&As[wr * 64 + i * 16 + rr][kb];
      #pragma unroll
      for (int j = 0; j < 4; j++) b[j] = *(const bf16x8*)&Bs[wc * 64 + j * 16 + rr][kb];
      #pragma unroll
      for (int i = 0; i < 4; i++)
        #pragma unroll
        for (int j = 0; j < 4; j++)
          acc[i][j] = __builtin_amdgcn_mfma_f32_16x16x32_bf16(a[i], b[j], acc[i][j], 0, 0, 0);
    }
    __syncthreads();
  }
  #pragma unroll
  for (int i = 0; i < 4; i++)
    #pragma unroll
    for (int l = 0; l < 4; l++) {
      int m = wr * 64 + i * 16 + quad * 4 + l;
      if (m < M) {
        int t = tl[m];
        float wp = wl[m];
        #pragma unroll
        for (int j = 0; j < 4; j++)
          atomicAdd(&out[(size_t)t * HH + h0 + wc * 64 + j * 16 + rr], acc[i][j][l] * wp);
      }
    }
}

extern "C" void kernel_launch(void* const* d_in, const int* in_sizes, int n_in,
                              void* d_out, int out_size, void* d_ws, size_t ws_size,
                              hipStream_t stream) {
  const float* hidden = (const float*)d_in[0];
  const float* rw     = (const float*)d_in[1];
  const float* bias   = (const float*)d_in[2];
  const float* w13    = (const float*)d_in[3];
  const float* w2     = (const float*)d_in[4];
  float* out = (float*)d_out;

  float* ws_f = (float*)d_ws;
  float* logits = ws_f;                                   // TT*40
  int* cnt = (int*)(logits + (size_t)TT * NE + TT);       // slack keeps 16B align
  int* offs = cnt + 32;
  int* cursor = offs + 32;
  int* tok4_id = cursor + 32;                             // TT*4
  float* tok4_w = (float*)(tok4_id + TT * TOPK);          // TT*4
  int* pair_tok = (int*)(tok4_w + TT * TOPK);             // TT*4
  float* pair_w = (float*)(pair_tok + TT * TOPK);         // TT*4
  int* wl_e = (int*)(pair_w + TT * TOPK);                 // 128
  int* wl_m0 = wl_e + 128;                                // 128
  int* nwork = wl_m0 + 128;                               // 64 (align pad)
  __bf16* hid_bf = (__bf16*)(nwork + 64);                 // TT*HH
  __bf16* h_buf = hid_bf + (size_t)TT * HH;               // (TT*4+128)*II

  k_logits<<<dim3(TT / 4), dim3(256), 0, stream>>>(hidden, rw, logits, cnt, cursor);
  k_route<<<dim3(TT / 4), dim3(256), 0, stream>>>(logits, bias, hidden, out,
                                                  cnt, tok4_id, tok4_w, hid_bf);
  k_scan<<<dim3(1), dim3(64), 0, stream>>>(cnt, offs, wl_e, wl_m0, nwork);
  k_scatter<<<dim3(TT * TOPK / 256), dim3(256), 0, stream>>>(tok4_id, tok4_w, offs,
                                                             cursor, pair_tok, pair_w);
  k_w13<<<dim3(MAXW, 8), dim3(256), 0, stream>>>(hid_bf, w13, cnt, offs, pair_tok,
                                                 wl_e, wl_m0, nwork, h_buf);
  k_w2<<<dim3(MAXW, 8), dim3(256), 0, stream>>>(h_buf, w2, cnt, offs, pair_tok, pair_w,
                                                wl_e, wl_m0, nwork, out);
}

// Round 5
// 341.897 us; speedup vs baseline: 5.8496x; 1.0620x over previous
//
#include <hip/hip_runtime.h>
#include <math.h>

#define TT 2048
#define HH 1024
#define NE 40
#define ER 32
#define II 512
#define TOPK 4
#define RSCALE 2.5f
#define MAXW 64    // max m-tiles of 256: 8192/256 + 32

typedef __bf16 bf16x8 __attribute__((ext_vector_type(8)));
typedef float f32x4 __attribute__((ext_vector_type(4)));

// ---------------- K1: fused router: logits(fp32) + softmax + top4 ----------
// One wave per token. fp32 logits REQUIRED (bf16 error ~2.6e-3 flips top-4).
// Also: out = hidden * zero_total, hid_bf = bf16(hidden) — single hidden read.
__global__ __launch_bounds__(256) void k_router(const float* __restrict__ hidden,
                                                const float* __restrict__ rw,
                                                const float* __restrict__ bias,
                                                float* __restrict__ out,
                                                int* __restrict__ tok4_id,
                                                float* __restrict__ tok4_w,
                                                __bf16* __restrict__ hid_bf) {
  int lane = threadIdx.x & 63;
  int t = blockIdx.x * 4 + (threadIdx.x >> 6);
  const float* hrow = hidden + (size_t)t * HH;
  float4 hv[4];
  #pragma unroll
  for (int c = 0; c < 4; c++) hv[c] = *(const float4*)(hrow + c * 256 + lane * 4);

  float mylg = -INFINITY;
  for (int e = 0; e < NE; e++) {
    const float* wrow = rw + (size_t)e * HH;
    float p = 0.f;
    #pragma unroll
    for (int c = 0; c < 4; c++) {
      float4 w4 = *(const float4*)(wrow + c * 256 + lane * 4);
      p += hv[c].x * w4.x + hv[c].y * w4.y + hv[c].z * w4.z + hv[c].w * w4.w;
    }
    #pragma unroll
    for (int off = 32; off; off >>= 1) p += __shfl_xor(p, off);
    if (lane == e) mylg = p;
  }
  float m = mylg;
  #pragma unroll
  for (int off = 32; off; off >>= 1) m = fmaxf(m, __shfl_xor(m, off));
  float p = (lane < NE) ? expf(mylg - m) : 0.f;
  float s = p;
  #pragma unroll
  for (int off = 32; off; off >>= 1) s += __shfl_xor(s, off);
  float score = p / s;
  float v = (lane < NE) ? score + bias[lane] : -INFINITY;
  int ids[TOPK]; float wv[TOPK];
  #pragma unroll
  for (int k = 0; k < TOPK; k++) {
    float mv = v;
    int mi = (lane < NE) ? lane : 63;
    #pragma unroll
    for (int off = 32; off; off >>= 1) {      // argmax, tie -> lower idx
      float ov = __shfl_xor(mv, off);
      int oi = __shfl_xor(mi, off);
      if (ov > mv || (ov == mv && oi < mi)) { mv = ov; mi = oi; }
    }
    ids[k] = mi;
    wv[k] = RSCALE * __shfl(score, mi);       // weight from UNBIASED score
    if (lane == mi) v = -INFINITY;
  }
  float zt = 0.f;
  #pragma unroll
  for (int k = 0; k < TOPK; k++) if (ids[k] >= ER) zt += wv[k];
  if (lane == 0) {
    #pragma unroll
    for (int k = 0; k < TOPK; k++) {
      tok4_id[t * TOPK + k] = ids[k];
      tok4_w[t * TOPK + k] = wv[k];
    }
  }
  #pragma unroll
  for (int c = 0; c < 4; c++) {
    int j = c * 256 + lane * 4;
    float4 h4 = hv[c];
    *(float4*)(out + (size_t)t * HH + j) =
        make_float4(h4.x * zt, h4.y * zt, h4.z * zt, h4.w * zt);
    union { __bf16 h[4]; uint2 u; } pk;
    pk.h[0] = (__bf16)h4.x; pk.h[1] = (__bf16)h4.y;
    pk.h[2] = (__bf16)h4.z; pk.h[3] = (__bf16)h4.w;
    *(uint2*)(hid_bf + (size_t)t * HH + j) = pk.u;
  }
}

// ---------------- K2: single-block count + scan + scatter (LDS counters) ---
__global__ __launch_bounds__(256) void k_scanscatter(const int* __restrict__ tok4_id,
                                                     const float* __restrict__ tok4_w,
                                                     int* __restrict__ cnt,
                                                     int* __restrict__ offs,
                                                     int* __restrict__ wl_e,
                                                     int* __restrict__ wl_m0,
                                                     int* __restrict__ nwork,
                                                     int* __restrict__ pair_tok,
                                                     float* __restrict__ pair_w) {
  __shared__ int scnt[32];
  __shared__ int scur[32];
  int tid = threadIdx.x;
  if (tid < 32) scnt[tid] = 0;
  __syncthreads();
  int ids[32]; float wv[32];
  #pragma unroll
  for (int i = 0; i < 32; i++) {              // 8192 entries, coalesced
    int idx = i * 256 + tid;
    ids[i] = tok4_id[idx];
    wv[i] = tok4_w[idx];
    if (ids[i] < ER) atomicAdd(&scnt[ids[i]], 1);
  }
  __syncthreads();
  if (tid < 64) {                             // one wave does the scan
    int lane = tid;
    int c = (lane < ER) ? scnt[lane] : 0;
    int ts = (c + 255) >> 8;                  // 256-row tiles
    int ps = c, pt = ts;
    #pragma unroll
    for (int off = 1; off < 32; off <<= 1) {
      int v1 = __shfl_up(ps, off);
      int v2 = __shfl_up(pt, off);
      if (lane >= off) { ps += v1; pt += v2; }
    }
    if (lane < ER) {
      int o = ps - c;
      offs[lane] = o; cnt[lane] = c; scur[lane] = o;
      int tb = pt - ts;
      for (int i = 0; i < ts; i++) { wl_e[tb + i] = lane; wl_m0[tb + i] = i * 256; }
    }
    if (lane == 31) *nwork = pt;
  }
  __syncthreads();
  #pragma unroll
  for (int i = 0; i < 32; i++) {
    if (ids[i] < ER) {
      int pos = atomicAdd(&scur[ids[i]], 1);  // absolute slot (scur seeded w/ offs)
      pair_tok[pos] = (i * 256 + tid) >> 2;
      pair_w[pos] = wv[i];
    }
  }
}

// ---------------- K3: h = silu(X@Wg^T)*(X@Wu^T), M=256 tile ----------------
// grid: MAXW x 16 (32 gate cols each). Weights fetched from HBM exactly once
// (1 m-tile/expert typical). Wave w: rows w*64..+64, all 32 gate+up cols.
__global__ __launch_bounds__(256) void k_w13(const __bf16* __restrict__ hid_bf,
                                             const float* __restrict__ w13,
                                             const int* __restrict__ cnt,
                                             const int* __restrict__ offs,
                                             const int* __restrict__ pair_tok,
                                             const int* __restrict__ wl_e,
                                             const int* __restrict__ wl_m0,
                                             const int* __restrict__ nwork,
                                             __bf16* __restrict__ h_buf) {
  int bx = blockIdx.x;
  if (bx >= *nwork) return;
  int e = wl_e[bx], m0w = wl_m0[bx];
  int M = cnt[e] - m0w; if (M > 256) M = 256;
  int base = offs[e] + m0w;
  int n0 = blockIdx.y * 32;

  __shared__ __bf16 As[256][72];   // pairs x k
  __shared__ __bf16 Bs[64][72];    // [0:32)=gate rows, [32:64)=up rows
  __shared__ int tl[256];

  int tid = threadIdx.x;
  int lane = tid & 63, w = tid >> 6;
  int quad = lane >> 4, rr = lane & 15;

  tl[tid] = pair_tok[base + ((tid < M) ? tid : 0)];

  const float* wg_base = w13 + (size_t)e * (2 * II) * HH + (size_t)n0 * HH;
  const float* wu_base = w13 + (size_t)e * (2 * II) * HH + (size_t)(II + n0) * HH;

  f32x4 accg[4][2] = {};
  f32x4 accu[4][2] = {};
  __syncthreads();

  for (int k0 = 0; k0 < HH; k0 += 64) {
    #pragma unroll
    for (int p = 0; p < 8; p++) {            // A: 256 x 64 bf16, tl-gathered
      int s = p * 256 + tid;
      int r = s >> 3, c = (s & 7) * 8;
      *(uint4*)&As[r][c] = *(const uint4*)(hid_bf + (size_t)tl[r] * HH + k0 + c);
    }
    #pragma unroll
    for (int p = 0; p < 4; p++) {            // B: 64 x 64 fp32 -> bf16
      int s = p * 256 + tid;
      int r = s >> 4, c = (s & 15) * 4;
      const float* src = ((r < 32) ? (wg_base + (size_t)r * HH)
                                   : (wu_base + (size_t)(r - 32) * HH)) + k0 + c;
      float4 v = *(const float4*)src;
      union { __bf16 h[4]; uint2 u; } pk;
      pk.h[0] = (__bf16)v.x; pk.h[1] = (__bf16)v.y;
      pk.h[2] = (__bf16)v.z; pk.h[3] = (__bf16)v.w;
      *(uint2*)&Bs[r][c] = pk.u;
    }
    __syncthreads();
    #pragma unroll
    for (int ks = 0; ks < 2; ks++) {
      int kb = ks * 32 + quad * 8;
      bf16x8 a[4], bg[2], bu[2];
      #pragma unroll
      for (int i = 0; i < 4; i++) a[i] = *(const bf16x8*)&As[w * 64 + i * 16 + rr][kb];
      #pragma unroll
      for (int j = 0; j < 2; j++) {
        bg[j] = *(const bf16x8*)&Bs[j * 16 + rr][kb];
        bu[j] = *(const bf16x8*)&Bs[32 + j * 16 + rr][kb];
      }
      #pragma unroll
      for (int i = 0; i < 4; i++)
        #pragma unroll
        for (int j = 0; j < 2; j++) {
          accg[i][j] = __builtin_amdgcn_mfma_f32_16x16x32_bf16(a[i], bg[j], accg[i][j], 0, 0, 0);
          accu[i][j] = __builtin_amdgcn_mfma_f32_16x16x32_bf16(a[i], bu[j], accu[i][j], 0, 0, 0);
        }
    }
    __syncthreads();
  }
  #pragma unroll
  for (int i = 0; i < 4; i++)
    #pragma unroll
    for (int j = 0; j < 2; j++)
      #pragma unroll
      for (int l = 0; l < 4; l++) {
        int m = w * 64 + i * 16 + quad * 4 + l;
        if (m < M) {
          float g = accg[i][j][l], u = accu[i][j][l];
          float hv = g / (1.f + expf(-g)) * u;
          h_buf[(size_t)(base + m) * II + n0 + j * 16 + rr] = (__bf16)hv;
        }
      }
}

// ---------------- K4: out[t] += w_p * (h @ w2[e]^T), M=256 tile ------------
// grid: MAXW x 16 (64 H-cols each). w2 fetched once.
__global__ __launch_bounds__(256) void k_w2(const __bf16* __restrict__ h_buf,
                                            const float* __restrict__ w2,
                                            const int* __restrict__ cnt,
                                            const int* __restrict__ offs,
                                            const int* __restrict__ pair_tok,
                                            const float* __restrict__ pair_w,
                                            const int* __restrict__ wl_e,
                                            const int* __restrict__ wl_m0,
                                            const int* __restrict__ nwork,
                                            float* __restrict__ out) {
  int bx = blockIdx.x;
  if (bx >= *nwork) return;
  int e = wl_e[bx], m0w = wl_m0[bx];
  int M = cnt[e] - m0w; if (M > 256) M = 256;
  int base = offs[e] + m0w;
  int h0 = blockIdx.y * 64;

  __shared__ __bf16 As[256][72];
  __shared__ __bf16 Bs[64][72];
  __shared__ int tl[256];
  __shared__ float wl[256];

  int tid = threadIdx.x;
  int lane = tid & 63, w = tid >> 6;
  int quad = lane >> 4, rr = lane & 15;

  {
    int ok = tid < M;
    tl[tid] = ok ? pair_tok[base + tid] : 0;
    wl[tid] = ok ? pair_w[base + tid] : 0.f;
  }
  const __bf16* h_base = h_buf + (size_t)base * II;
  const float* w_base = w2 + (size_t)e * HH * II + (size_t)h0 * II;

  f32x4 acc[4][4] = {};
  __syncthreads();

  for (int k0 = 0; k0 < II; k0 += 64) {
    #pragma unroll
    for (int p = 0; p < 8; p++) {            // A: 256 contiguous h rows
      int s = p * 256 + tid;                 // (rows >= M: 0xAA junk ~1e-13, masked)
      int r = s >> 3, c = (s & 7) * 8;
      *(uint4*)&As[r][c] = *(const uint4*)(h_base + (size_t)r * II + k0 + c);
    }
    #pragma unroll
    for (int p = 0; p < 4; p++) {            // B: 64 x 64 fp32 -> bf16
      int s = p * 256 + tid;
      int r = s >> 4, c = (s & 15) * 4;
      float4 v = *(const float4*)(w_base + (size_t)r * II + k0 + c);
      union { __bf16 h[4]; uint2 u; } pk;
      pk.h[0] = (__bf16)v.x; pk.h[1] = (__bf16)v.y;
      pk.h[2] = (__bf16)v.z; pk.h[3] = (__bf16)v.w;
      *(uint2*)&Bs[r][c] = pk.u;
    }
    __syncthreads();
    #pragma unroll
    for (int ks = 0; ks < 2; ks++) {
      int kb = ks * 32 + quad * 8;
      bf16x8 a[4], b[4];
      #pragma unroll
      for (int i = 0; i < 4; i++) a[i] = *(const bf16x8*)&As[w * 64 + i * 16 + rr][kb];
      #pragma unroll
      for (int j = 0; j < 4; j++) b[j] = *(const bf16x8*)&Bs[j * 16 + rr][kb];
      #pragma unroll
      for (int i = 0; i < 4; i++)
        #pragma unroll
        for (int j = 0; j < 4; j++)
          acc[i][j] = __builtin_amdgcn_mfma_f32_16x16x32_bf16(a[i], b[j], acc[i][j], 0, 0, 0);
    }
    __syncthreads();
  }
  #pragma unroll
  for (int i = 0; i < 4; i++)
    #pragma unroll
    for (int l = 0; l < 4; l++) {
      int m = w * 64 + i * 16 + quad * 4 + l;
      if (m < M) {
        int t = tl[m];
        float wp = wl[m];
        #pragma unroll
        for (int j = 0; j < 4; j++)
          atomicAdd(&out[(size_t)t * HH + h0 + j * 16 + rr], acc[i][j][l] * wp);
      }
    }
}

extern "C" void kernel_launch(void* const* d_in, const int* in_sizes, int n_in,
                              void* d_out, int out_size, void* d_ws, size_t ws_size,
                              hipStream_t stream) {
  const float* hidden = (const float*)d_in[0];
  const float* rw     = (const float*)d_in[1];
  const float* bias   = (const float*)d_in[2];
  const float* w13    = (const float*)d_in[3];
  const float* w2     = (const float*)d_in[4];
  float* out = (float*)d_out;

  int* ws_i = (int*)d_ws;
  int* tok4_id = ws_i;                                    // TT*4
  float* tok4_w = (float*)(tok4_id + TT * TOPK);          // TT*4
  int* pair_tok = (int*)(tok4_w + TT * TOPK);             // TT*4
  float* pair_w = (float*)(pair_tok + TT * TOPK);         // TT*4
  int* cnt = (int*)(pair_w + TT * TOPK);                  // 32
  int* offs = cnt + 32;                                   // 32
  int* wl_e = offs + 32;                                  // 64
  int* wl_m0 = wl_e + 64;                                 // 64
  int* nwork = wl_m0 + 64;                                // + pad to 16B align
  __bf16* hid_bf = (__bf16*)(nwork + 64);                 // TT*HH
  __bf16* h_buf = hid_bf + (size_t)TT * HH;               // (TT*4+256)*II

  k_router<<<dim3(TT / 4), dim3(256), 0, stream>>>(hidden, rw, bias, out,
                                                   tok4_id, tok4_w, hid_bf);
  k_scanscatter<<<dim3(1), dim3(256), 0, stream>>>(tok4_id, tok4_w, cnt, offs,
                                                   wl_e, wl_m0, nwork, pair_tok, pair_w);
  k_w13<<<dim3(MAXW, 16), dim3(256), 0, stream>>>(hid_bf, w13, cnt, offs, pair_tok,
                                                  wl_e, wl_m0, nwork, h_buf);
  k_w2<<<dim3(MAXW, 16), dim3(256), 0, stream>>>(h_buf, w2, cnt, offs, pair_tok, pair_w,
                                                 wl_e, wl_m0, nwork, out);
}